// Round 6
// baseline (576.113 us; speedup 1.0000x reference)
//
#include <hip/hip_runtime.h>
#include <hip/hip_bf16.h>
#include <stdint.h>

#define DIM    4096
#define NH     32
#define NKVH   8
#define HD     128
#define SEQ    2048
#define BATCH  2
#define MTOT   (BATCH*SEQ)      // 4096
#define SCALE  0.08838834764831845f

typedef __bf16 bf16_t;
typedef __bf16 bf16x8 __attribute__((ext_vector_type(8)));
typedef float  f32x4  __attribute__((ext_vector_type(4)));

#define AS1 __attribute__((address_space(1)))
#define AS3 __attribute__((address_space(3)))

__device__ __forceinline__ void gload_lds16(const void* g, void* l) {
    __builtin_amdgcn_global_load_lds((const AS1 void*)g, (AS3 void*)l, 16, 0, 0);
}

__device__ __forceinline__ void fence_barrier() {
    asm volatile("" ::: "memory");
    __builtin_amdgcn_s_barrier();
    asm volatile("" ::: "memory");
}

// ---------------- f32 -> bf16 converts ----------------
__global__ __launch_bounds__(256)
void cvt_f32_bf16(const float* __restrict__ in, bf16_t* __restrict__ out, int n4) {
    for (int i = blockIdx.x * blockDim.x + threadIdx.x; i < n4;
         i += gridDim.x * blockDim.x) {
        float4 v = reinterpret_cast<const float4*>(in)[i];
        union { bf16_t b[4]; uint2 u; } t;
        t.b[0] = (bf16_t)v.x; t.b[1] = (bf16_t)v.y;
        t.b[2] = (bf16_t)v.z; t.b[3] = (bf16_t)v.w;
        reinterpret_cast<uint2*>(out)[i] = t.u;
    }
}

__global__ __launch_bounds__(256)
void cvt_weights(const float* __restrict__ wq, const float* __restrict__ wk,
                 const float* __restrict__ wv, const float* __restrict__ wo,
                 bf16_t* __restrict__ out) {
    const int n0 = DIM * DIM / 4;
    const int n1 = NKVH * HD * DIM / 4;
    const int n2 = NKVH * HD * DIM / 4;
    const int n3 = DIM * DIM / 4;
    const int ntot = n0 + n1 + n2 + n3;
    for (int i = blockIdx.x * blockDim.x + threadIdx.x; i < ntot;
         i += gridDim.x * blockDim.x) {
        const float* src;
        int k = i;
        if (k < n0) src = wq;
        else if ((k -= n0) < n1) src = wk;
        else if ((k -= n1) < n2) src = wv;
        else { k -= n2; src = wo; }
        float4 v = reinterpret_cast<const float4*>(src)[k];
        union { bf16_t b[4]; uint2 u; } t;
        t.b[0] = (bf16_t)v.x; t.b[1] = (bf16_t)v.y;
        t.b[2] = (bf16_t)v.z; t.b[3] = (bf16_t)v.w;
        reinterpret_cast<uint2*>(out)[i] = t.u;
    }
}

// ============ 256x256-tile 8-wave GEMM — m201-faithful 4-phase K-loop ======
// 512 threads = 8 waves (2 wm x 4 wn); wave tile 128x64.
// Per K-tile j (slot s=j&1), 4 phases; phase = one C-quadrant (16 MFMA, K=64):
//  P1: read a(mh0)[8]+b(np0)[4]; stage A(j+1)h0; lgkm(8); bar; lgkm(0);
//      prio1; MFMA mh0 x ni01; prio0; bar
//  P2: read b(np1)[4];           stage A(j+1)h1; bar; lgkm(0);
//      prio1; MFMA mh0 x ni23; prio0; bar
//  P3: read a(mh1)[8];           stage B(j+2)h0; bar; lgkm(0);
//      prio1; MFMA mh1 x ni01; prio0; bar
//  P4:                           stage B(j+2)h1; bar;
//      prio1; MFMA mh1 x ni23; prio0; vmcnt(4); bar
// Overwrite safety: A-half reads drain at P3's lgkm(0)+bar (stage at next P1/P2);
// B-half reads drain at P2's lgkm(0)+bar (stage at P3/P4). vmcnt(4) leaves only
// B(j+2)'s 4 loads in flight => tile j+1 fully landed before next iter.

__device__ __forceinline__ void stage_half(const bf16_t* gbase, int kt, int h,
                                           bf16_t* ldsdst, int tid, int w) {
#pragma unroll
    for (int t2 = 0; t2 < 2; ++t2) {
        int s = t2 * 512 + tid;
        int r = s >> 3, c = s & 7;
        gload_lds16(gbase + (size_t)(h * 128 + r) * DIM + kt + ((c ^ (r & 7)) * 8),
                    ldsdst + (size_t)(t2 * 512 + w * 64) * 8);
    }
}

__device__ __forceinline__ void read_a4(bf16x8 a[4][2], const bf16_t* Ahalf,
                                        int mh, int lr, int lg) {
#pragma unroll
    for (int mi = 0; mi < 4; ++mi) {
        int r = mh * 64 + mi * 16 + lr;
#pragma unroll
        for (int kk = 0; kk < 2; ++kk)
            a[mi][kk] = *(const bf16x8*)(Ahalf + r * 64 + ((kk * 4 + lg) ^ (r & 7)) * 8);
    }
}

__device__ __forceinline__ void read_b2(bf16x8 b[2][2], const bf16_t* Bhalf,
                                        int np, int rb, int lg) {
#pragma unroll
    for (int ni = 0; ni < 2; ++ni) {
        int r = rb + (np * 2 + ni) * 16;
#pragma unroll
        for (int kk = 0; kk < 2; ++kk)
            b[ni][kk] = *(const bf16x8*)(Bhalf + r * 64 + ((kk * 4 + lg) ^ (r & 7)) * 8);
    }
}

template<int MODE>
__global__ __launch_bounds__(512, 2)
void gemm8(const bf16_t* __restrict__ A,
           const bf16_t* __restrict__ B0,
           float* __restrict__ outF,
           bf16_t* __restrict__ outQ,
           bf16_t* __restrict__ outK,
           bf16_t* __restrict__ outV,
           const float* __restrict__ cosT,
           const float* __restrict__ sinT) {
    __shared__ __align__(16) bf16_t As[2][2][128 * 64];
    __shared__ __align__(16) bf16_t Bs[2][2][128 * 64];

    const int tid = threadIdx.x;
    const int l = tid & 63;
    const int w = tid >> 6;           // 0..7
    const int wm = w >> 2, wn = w & 3;
    const int lr = l & 15, lg = l >> 4;
    const int rb = (wn & 1) * 64 + lr;

    // XCD-aware bijective swizzle (nwg % 8 == 0 for both grids)
    constexpr int NY = (MODE == 3) ? 24 : 16;
    const int nwg = 16 * NY;
    const int bid = blockIdx.y * gridDim.x + blockIdx.x;
    const int swz = (bid & 7) * (nwg >> 3) + (bid >> 3);
    const int bx = swz / NY;
    const int ct = swz - bx * NY;
    const int rowBase = bx * 256;

    const bf16_t* Ap = A + (size_t)rowBase * DIM;
    const bf16_t* Bp = B0 + (size_t)ct * 256 * DIM;

    f32x4 acc[8][4] = {};
    bf16x8 aq[4][2];     // current mi-half operands [mi'][kk]
    bf16x8 bA[2][2];     // ni 0,1  [ni'][kk]
    bf16x8 bB[2][2];     // ni 2,3

    const int NT = DIM / 64;   // 64

    // ---- prologue: B(0), A(0), B(1); gate tile 0 ----
    stage_half(Bp, 0,  0, &Bs[0][0][0], tid, w);
    stage_half(Bp, 0,  1, &Bs[0][1][0], tid, w);
    stage_half(Ap, 0,  0, &As[0][0][0], tid, w);
    stage_half(Ap, 0,  1, &As[0][1][0], tid, w);
    stage_half(Bp, 64, 0, &Bs[1][0][0], tid, w);
    stage_half(Bp, 64, 1, &Bs[1][1][0], tid, w);
    asm volatile("s_waitcnt vmcnt(4)" ::: "memory");
    fence_barrier();

    for (int j = 0; j < NT; ++j) {
        const int s = j & 1;
        const bf16_t* Ah = &As[s][wm][0];
        const bf16_t* Bh = &Bs[s][wn >> 1][0];
        const int ktA = ((j + 1 < NT) ? j + 1 : NT - 1) * 64;
        const int ktB = ((j + 2 < NT) ? j + 2 : NT - 1) * 64;

        // ---------- P1 ----------
        read_a4(aq, Ah, 0, lr, lg);
        read_b2(bA, Bh, 0, rb, lg);
        stage_half(Ap, ktA, 0, &As[s ^ 1][0][0], tid, w);
        asm volatile("s_waitcnt lgkmcnt(8)" ::: "memory");
        fence_barrier();
        asm volatile("s_waitcnt lgkmcnt(0)" ::: "memory");
        __builtin_amdgcn_s_setprio(1);
#pragma unroll
        for (int kk = 0; kk < 2; ++kk)
#pragma unroll
            for (int mi = 0; mi < 4; ++mi) {
                acc[mi][0] = __builtin_amdgcn_mfma_f32_16x16x32_bf16(aq[mi][kk], bA[0][kk], acc[mi][0], 0, 0, 0);
                acc[mi][1] = __builtin_amdgcn_mfma_f32_16x16x32_bf16(aq[mi][kk], bA[1][kk], acc[mi][1], 0, 0, 0);
            }
        __builtin_amdgcn_s_setprio(0);
        fence_barrier();

        // ---------- P2 ----------
        read_b2(bB, Bh, 1, rb, lg);
        stage_half(Ap, ktA, 1, &As[s ^ 1][1][0], tid, w);
        fence_barrier();
        asm volatile("s_waitcnt lgkmcnt(0)" ::: "memory");
        __builtin_amdgcn_s_setprio(1);
#pragma unroll
        for (int kk = 0; kk < 2; ++kk)
#pragma unroll
            for (int mi = 0; mi < 4; ++mi) {
                acc[mi][2] = __builtin_amdgcn_mfma_f32_16x16x32_bf16(aq[mi][kk], bB[0][kk], acc[mi][2], 0, 0, 0);
                acc[mi][3] = __builtin_amdgcn_mfma_f32_16x16x32_bf16(aq[mi][kk], bB[1][kk], acc[mi][3], 0, 0, 0);
            }
        __builtin_amdgcn_s_setprio(0);
        fence_barrier();

        // ---------- P3 ----------
        read_a4(aq, Ah, 1, lr, lg);
        stage_half(Bp, ktB, 0, &Bs[s][0][0], tid, w);
        fence_barrier();
        asm volatile("s_waitcnt lgkmcnt(0)" ::: "memory");
        __builtin_amdgcn_s_setprio(1);
#pragma unroll
        for (int kk = 0; kk < 2; ++kk)
#pragma unroll
            for (int mi = 0; mi < 4; ++mi) {
                acc[mi + 4][0] = __builtin_amdgcn_mfma_f32_16x16x32_bf16(aq[mi][kk], bA[0][kk], acc[mi + 4][0], 0, 0, 0);
                acc[mi + 4][1] = __builtin_amdgcn_mfma_f32_16x16x32_bf16(aq[mi][kk], bA[1][kk], acc[mi + 4][1], 0, 0, 0);
            }
        __builtin_amdgcn_s_setprio(0);
        fence_barrier();

        // ---------- P4 ----------
        stage_half(Bp, ktB, 1, &Bs[s][1][0], tid, w);
        fence_barrier();
        __builtin_amdgcn_s_setprio(1);
#pragma unroll
        for (int kk = 0; kk < 2; ++kk)
#pragma unroll
            for (int mi = 0; mi < 4; ++mi) {
                acc[mi + 4][2] = __builtin_amdgcn_mfma_f32_16x16x32_bf16(aq[mi][kk], bB[0][kk], acc[mi + 4][2], 0, 0, 0);
                acc[mi + 4][3] = __builtin_amdgcn_mfma_f32_16x16x32_bf16(aq[mi][kk], bB[1][kk], acc[mi + 4][3], 0, 0, 0);
            }
        __builtin_amdgcn_s_setprio(0);
        asm volatile("s_waitcnt vmcnt(4)" ::: "memory");
        fence_barrier();
    }

    // ---- epilogue ----
#pragma unroll
    for (int mi = 0; mi < 8; ++mi) {
        int gmBase = rowBase + wm * 128 + mi * 16 + lg * 4;
#pragma unroll
        for (int ni = 0; ni < 4; ++ni) {
            f32x4 v4 = acc[mi][ni];
            int gn = ct * 256 + wn * 64 + ni * 16 + lr;
            if (MODE == 0) {
#pragma unroll
                for (int i = 0; i < 4; ++i)
                    outF[(size_t)(gmBase + i) * DIM + gn] = v4[i];
            } else { // MODE 3: fused QKV
                if (ct < 16) {          // Q rope -> Qr[b][h][s][d]
                    int h = gn >> 7, d = gn & 127, pi2 = d >> 1;
#pragma unroll
                    for (int i = 0; i < 4; ++i) {
                        float v = v4[i];
                        float pvv = __shfl_xor(v, 1);
                        int gm = gmBase + i;
                        int bb = gm >> 11, sidx = gm & (SEQ - 1);
                        float c = cosT[sidx * 64 + pi2], sn = sinT[sidx * 64 + pi2];
                        float o = (d & 1) ? (pvv * sn + v * c) : (v * c - pvv * sn);
                        outQ[((size_t)(bb * NH + h) * SEQ + sidx) * HD + d] = (bf16_t)o;
                    }
                } else if (ct < 20) {   // K rope -> Kr[b][kvh][s][d]
                    int kn = gn - 4096;
                    int h = kn >> 7, d = kn & 127, pi2 = d >> 1;
#pragma unroll
                    for (int i = 0; i < 4; ++i) {
                        float v = v4[i];
                        float pvv = __shfl_xor(v, 1);
                        int gm = gmBase + i;
                        int bb = gm >> 11, sidx = gm & (SEQ - 1);
                        float c = cosT[sidx * 64 + pi2], sn = sinT[sidx * 64 + pi2];
                        float o = (d & 1) ? (pvv * sn + v * c) : (v * c - pvv * sn);
                        outK[((size_t)(bb * NKVH + h) * SEQ + sidx) * HD + d] = (bf16_t)o;
                    }
                } else {                // V transpose -> Vt[b][kvh][d][s]
                    int vn = gn - 5120;
                    int kvh = vn >> 7, d = vn & 127;
#pragma unroll
                    for (int i = 0; i < 4; ++i) {
                        float dummy = __shfl_xor(v4[i], 1); (void)dummy;
                        int gm = gmBase + i;
                        int bb = gm >> 11, sidx = gm & (SEQ - 1);
                        outV[((size_t)(bb * NKVH + kvh) * HD + d) * SEQ + sidx] = (bf16_t)v4[i];
                    }
                }
            }
        }
    }
}

// ---------------- flash attention (causal, GQA) ---------------- (unchanged)
__global__ __launch_bounds__(256, 2)
void attn_fwd(const bf16_t* __restrict__ Qr,
              const bf16_t* __restrict__ Kr,
              const bf16_t* __restrict__ Vt,
              bf16_t* __restrict__ Ob) {
    __shared__ __align__(16) bf16_t Ks[2][64 * 128];   // [kv][d], swizzled
    __shared__ __align__(16) bf16_t Vs[2][128 * 64];   // [d][kv], swizzled
    __shared__ __align__(16) bf16_t Ps[4][32 * 64];    // per-wave P, swizzled

    const int tid = threadIdx.x;
    const int l  = tid & 63;
    const int w  = tid >> 6;
    const int lr = l & 15, lg = l >> 4;
    const int e  = lr & 7;

    const int qt  = 15 - (blockIdx.x >> 6);
    const int bh  = blockIdx.x & 63;
    const int b   = bh >> 5;
    const int h   = bh & 31;
    const int kvh = h >> 2;
    const int q0  = qt * 128;
    const int nt  = 2 * qt + 2;
    const int qmin = q0 + w * 32;

    const bf16_t* kbase = Kr + (size_t)(b * NKVH + kvh) * SEQ * HD;
    const bf16_t* vbase = Vt + (size_t)(b * NKVH + kvh) * HD * SEQ;

    bf16x8 qf[2][4];
    const bf16_t* qp = Qr + ((size_t)(b * NH + h) * SEQ + qmin + lr) * HD;
#pragma unroll
    for (int mi = 0; mi < 2; ++mi)
#pragma unroll
        for (int kk = 0; kk < 4; ++kk)
            qf[mi][kk] = *(const bf16x8*)(qp + (size_t)mi * 16 * HD + kk * 32 + lg * 8);

    f32x4 oacc[2][8] = {};
    float mrow[2] = {-1e30f, -1e30f};
    float lsum[2] = {0.f, 0.f};

#pragma unroll
    for (int t2 = 0; t2 < 4; ++t2) {
        int s = t2 * 256 + tid;
        { int r = s >> 4, g = (s & 15) ^ (r & 7);
          gload_lds16(kbase + (size_t)r * HD + g * 8,
                      &Ks[0][(size_t)(t2 * 256 + w * 64) * 8]); }
        { int r = s >> 3, g = (s & 7) ^ (r & 7);
          gload_lds16(vbase + (size_t)r * SEQ + g * 8,
                      &Vs[0][(size_t)(t2 * 256 + w * 64) * 8]); }
    }
    __syncthreads();

    int cur = 0;
    for (int t = 0; t < nt; ++t) {
        if (t + 1 < nt) {
            const int kv1 = (t + 1) * 64;
#pragma unroll
            for (int t2 = 0; t2 < 4; ++t2) {
                int s = t2 * 256 + tid;
                { int r = s >> 4, g = (s & 15) ^ (r & 7);
                  gload_lds16(kbase + (size_t)(kv1 + r) * HD + g * 8,
                              &Ks[cur ^ 1][(size_t)(t2 * 256 + w * 64) * 8]); }
                { int r = s >> 3, g = (s & 7) ^ (r & 7);
                  gload_lds16(vbase + (size_t)r * SEQ + kv1 + g * 8,
                              &Vs[cur ^ 1][(size_t)(t2 * 256 + w * 64) * 8]); }
            }
        }

        const bool active = (t * 64) <= (qmin + 31);
        if (active) {
            const bool needMask = (t * 64 + 63) > qmin;

            f32x4 sf[2][4] = {};
#pragma unroll
            for (int kk = 0; kk < 4; ++kk)
#pragma unroll
                for (int nf = 0; nf < 4; ++nf) {
                    bf16x8 kf = *(const bf16x8*)(
                        &Ks[cur][(nf * 16 + lr) * 128 + ((kk * 4 + lg) ^ e) * 8]);
#pragma unroll
                    for (int mi = 0; mi < 2; ++mi)
                        sf[mi][nf] = __builtin_amdgcn_mfma_f32_16x16x32_bf16(
                            kf, qf[mi][kk], sf[mi][nf], 0, 0, 0);
                }

            float aO[2][4];
#pragma unroll
            for (int mi = 0; mi < 2; ++mi) {
                const int qrow = qmin + mi * 16 + lr;
                float mt = -1e30f;
#pragma unroll
                for (int nf = 0; nf < 4; ++nf)
#pragma unroll
                    for (int i = 0; i < 4; ++i) {
                        float sc = sf[mi][nf][i] * SCALE;
                        if (needMask && (t * 64 + nf * 16 + lg * 4 + i) > qrow)
                            sc = -1e30f;
                        sf[mi][nf][i] = sc;
                        mt = fmaxf(mt, sc);
                    }
                mt = fmaxf(mt, __shfl_xor(mt, 16));
                mt = fmaxf(mt, __shfl_xor(mt, 32));
                float mnew = fmaxf(mrow[mi], mt);
                float alpha = __expf(mrow[mi] - mnew);
                mrow[mi] = mnew;
                float rs = 0.f;
#pragma unroll
                for (int nf = 0; nf < 4; ++nf)
#pragma unroll
                    for (int i = 0; i < 4; ++i) {
                        float p = __expf(sf[mi][nf][i] - mnew);
                        sf[mi][nf][i] = p;
                        rs += p;
                    }
                rs += __shfl_xor(rs, 16);
                rs += __shfl_xor(rs, 32);
                lsum[mi] = lsum[mi] * alpha + rs;
#pragma unroll
                for (int i = 0; i < 4; ++i)
                    aO[mi][i] = __shfl(alpha, lg * 4 + i);
            }

#pragma unroll
            for (int mi = 0; mi < 2; ++mi)
#pragma unroll
                for (int df = 0; df < 8; ++df)
#pragma unroll
                    for (int i = 0; i < 4; ++i)
                        oacc[mi][df][i] *= aO[mi][i];

#pragma unroll
            for (int mi = 0; mi < 2; ++mi)
#pragma unroll
                for (int nf = 0; nf < 4; ++nf) {
                    union { bf16_t bb[4]; uint2 u; } pk;
#pragma unroll
                    for (int i = 0; i < 4; ++i) pk.bb[i] = (bf16_t)sf[mi][nf][i];
                    int addr = (mi * 16 + lr) * 64 +
                               (((nf * 2 + (lg >> 1)) ^ e) << 3) + (lg & 1) * 4;
                    *(uint2*)(&Ps[w][addr]) = pk.u;
                }
            asm volatile("s_waitcnt lgkmcnt(0)" ::: "memory");
            __builtin_amdgcn_sched_barrier(0);

            bf16x8 pf[2][2];
#pragma unroll
            for (int mi = 0; mi < 2; ++mi)
#pragma unroll
                for (int k2 = 0; k2 < 2; ++k2)
                    pf[mi][k2] = *(const bf16x8*)(
                        &Ps[w][(mi * 16 + lr) * 64 + ((k2 * 4 + lg) ^ e) * 8]);
#pragma unroll
            for (int df = 0; df < 8; ++df)
#pragma unroll
                for (int k2 = 0; k2 < 2; ++k2) {
                    bf16x8 vf = *(const bf16x8*)(
                        &Vs[cur][(df * 16 + lr) * 64 + ((k2 * 4 + lg) ^ e) * 8]);
#pragma unroll
                    for (int mi = 0; mi < 2; ++mi)
                        oacc[mi][df] = __builtin_amdgcn_mfma_f32_16x16x32_bf16(
                            pf[mi][k2], vf, oacc[mi][df], 0, 0, 0);
                }
        }
        __syncthreads();
        cur ^= 1;
    }

#pragma unroll
    for (int mi = 0; mi < 2; ++mi) {
        float ls[4];
#pragma unroll
        for (int i = 0; i < 4; ++i)
            ls[i] = 1.f / __shfl(lsum[mi], lg * 4 + i);
#pragma unroll
        for (int df = 0; df < 8; ++df)
#pragma unroll
            for (int i = 0; i < 4; ++i) {
                float o = oacc[mi][df][i] * ls[i];
                int gm = b * SEQ + qmin + mi * 16 + lg * 4 + i;
                int gn = h * HD + df * 16 + lr;
                Ob[(size_t)gm * DIM + gn] = (bf16_t)o;
            }
    }
}

// ---------------- launcher ----------------
extern "C" void kernel_launch(void* const* d_in, const int* in_sizes, int n_in,
                              void* d_out, int out_size, void* d_ws, size_t ws_size,
                              hipStream_t stream) {
    const float* x    = (const float*)d_in[0];
    const float* cosT = (const float*)d_in[1];
    const float* sinT = (const float*)d_in[2];
    const float* wq   = (const float*)d_in[3];
    const float* wk   = (const float*)d_in[4];
    const float* wv   = (const float*)d_in[5];
    const float* wo   = (const float*)d_in[6];

    bf16_t* p = (bf16_t*)d_ws;
    bf16_t* xb  = p; p += (size_t)MTOT * DIM;
    bf16_t* wb  = p; p += (size_t)(DIM + 2 * NKVH * HD + DIM) * DIM;  // wq|wk|wv|wo
    bf16_t* Qr  = p; p += (size_t)MTOT * DIM;
    bf16_t* Kr  = p; p += (size_t)BATCH * NKVH * SEQ * HD;
    bf16_t* Vt  = p; p += (size_t)BATCH * NKVH * HD * SEQ;
    bf16_t* Ob  = p; p += (size_t)MTOT * DIM;

    bf16_t* wob = wb + (size_t)(DIM + 2 * NKVH * HD) * DIM;  // wo region

    cvt_f32_bf16<<<2048, 256, 0, stream>>>(x, xb, MTOT * DIM / 4);
    cvt_weights<<<2048, 256, 0, stream>>>(wq, wk, wv, wo, wb);

    // fused QKV: N = 4096 (Q) + 1024 (K) + 1024 (V) = 6144 -> 24 col tiles
    gemm8<3><<<dim3(16, 24), 512, 0, stream>>>(
        xb, wb, nullptr, Qr, Kr, Vt, cosT, sinT);

    attn_fwd<<<1024, 256, 0, stream>>>(Qr, Kr, Vt, Ob);

    gemm8<0><<<dim3(16, 16), 512, 0, stream>>>(
        Ob, wob, (float*)d_out, nullptr, nullptr, nullptr, nullptr, nullptr);
}

// Round 7
// 517.028 us; speedup vs baseline: 1.1143x; 1.1143x over previous
//
#include <hip/hip_runtime.h>
#include <hip/hip_bf16.h>
#include <stdint.h>

#define DIM    4096
#define NH     32
#define NKVH   8
#define HD     128
#define SEQ    2048
#define BATCH  2
#define MTOT   (BATCH*SEQ)      // 4096
#define SCALE  0.08838834764831845f

typedef __bf16 bf16_t;
typedef __bf16 bf16x8 __attribute__((ext_vector_type(8)));
typedef float  f32x4  __attribute__((ext_vector_type(4)));

#define AS1 __attribute__((address_space(1)))
#define AS3 __attribute__((address_space(3)))

__device__ __forceinline__ void gload_lds16(const void* g, void* l) {
    __builtin_amdgcn_global_load_lds((const AS1 void*)g, (AS3 void*)l, 16, 0, 0);
}

__device__ __forceinline__ void fence_barrier() {
    asm volatile("" ::: "memory");
    __builtin_amdgcn_s_barrier();
    asm volatile("" ::: "memory");
}

// ---------------- f32 -> bf16 converts ----------------
__global__ __launch_bounds__(256)
void cvt_f32_bf16(const float* __restrict__ in, bf16_t* __restrict__ out, int n4) {
    for (int i = blockIdx.x * blockDim.x + threadIdx.x; i < n4;
         i += gridDim.x * blockDim.x) {
        float4 v = reinterpret_cast<const float4*>(in)[i];
        union { bf16_t b[4]; uint2 u; } t;
        t.b[0] = (bf16_t)v.x; t.b[1] = (bf16_t)v.y;
        t.b[2] = (bf16_t)v.z; t.b[3] = (bf16_t)v.w;
        reinterpret_cast<uint2*>(out)[i] = t.u;
    }
}

__global__ __launch_bounds__(256)
void cvt_weights(const float* __restrict__ wq, const float* __restrict__ wk,
                 const float* __restrict__ wv, const float* __restrict__ wo,
                 bf16_t* __restrict__ out) {
    const int n0 = DIM * DIM / 4;
    const int n1 = NKVH * HD * DIM / 4;
    const int n2 = NKVH * HD * DIM / 4;
    const int n3 = DIM * DIM / 4;
    const int ntot = n0 + n1 + n2 + n3;
    for (int i = blockIdx.x * blockDim.x + threadIdx.x; i < ntot;
         i += gridDim.x * blockDim.x) {
        const float* src;
        int k = i;
        if (k < n0) src = wq;
        else if ((k -= n0) < n1) src = wk;
        else if ((k -= n1) < n2) src = wv;
        else { k -= n2; src = wo; }
        float4 v = reinterpret_cast<const float4*>(src)[k];
        union { bf16_t b[4]; uint2 u; } t;
        t.b[0] = (bf16_t)v.x; t.b[1] = (bf16_t)v.y;
        t.b[2] = (bf16_t)v.z; t.b[3] = (bf16_t)v.w;
        reinterpret_cast<uint2*>(out)[i] = t.u;
    }
}

// ===== 256x256-tile 8-wave GEMM — hybrid: reads-a-phase-early + counted waits
// 512 threads = 8 waves (2 wm x 4 wn); wave tile 128x64; BK=64.
// Quadrants: q1=(A0,B01) q2=(A0,B23) q3=(A1,B01) q4=(A1,B23), 16 MFMA each.
// Per K-tile j (slot s=j&1); entering: a0,bA(j) in flight (issued P4-tail):
//  P1: issue bB(j)[4];  stage A(j+1)h0; lgkm(4)  [a0,bA drained]; q1; bar
//  P2: issue a1(j)[8];  stage A(j+1)h1; lgkm(8)  [bB drained];    q2; bar
//  P3:                  stage B(j+2)h0; lgkm(0)  [a1 drained];    q3; bar
//  P4:                  stage B(j+2)h1;                           q4;
//      vmcnt(4) [A(j+1) landed, B(j+2) in flight]; bar;
//      issue a0,bA(j+1)[12] from slots s^1.
// Overwrite safety: A-slot reads drain by P3(j)'s lgkm(0)+bar, stage at
// P1/P2(j+1). B-slot reads drain by P2's lgkm(8)+bar, stage at P3/P4.

__device__ __forceinline__ void stage_half(const bf16_t* gbase, int kt, int h,
                                           bf16_t* ldsdst, int tid, int w) {
#pragma unroll
    for (int t2 = 0; t2 < 2; ++t2) {
        int s = t2 * 512 + tid;
        int r = s >> 3, c = s & 7;
        gload_lds16(gbase + (size_t)(h * 128 + r) * DIM + kt + ((c ^ (r & 7)) * 8),
                    ldsdst + (size_t)(t2 * 512 + w * 64) * 8);
    }
}

__device__ __forceinline__ void read_a4(bf16x8 a[4][2], const bf16_t* Ahalf,
                                        int mh, int lr, int lg) {
#pragma unroll
    for (int mi = 0; mi < 4; ++mi) {
        int r = mh * 64 + mi * 16 + lr;
#pragma unroll
        for (int kk = 0; kk < 2; ++kk)
            a[mi][kk] = *(const bf16x8*)(Ahalf + r * 64 + ((kk * 4 + lg) ^ (r & 7)) * 8);
    }
}

__device__ __forceinline__ void read_b2(bf16x8 b[2][2], const bf16_t* Bhalf,
                                        int np, int rb, int lg) {
#pragma unroll
    for (int ni = 0; ni < 2; ++ni) {
        int r = rb + (np * 2 + ni) * 16;
#pragma unroll
        for (int kk = 0; kk < 2; ++kk)
            b[ni][kk] = *(const bf16x8*)(Bhalf + r * 64 + ((kk * 4 + lg) ^ (r & 7)) * 8);
    }
}

template<int MODE>
__global__ __launch_bounds__(512, 2)
void gemm8(const bf16_t* __restrict__ A,
           const bf16_t* __restrict__ B0,
           float* __restrict__ outF,
           bf16_t* __restrict__ outQ,
           bf16_t* __restrict__ outK,
           bf16_t* __restrict__ outV,
           const float* __restrict__ cosT,
           const float* __restrict__ sinT) {
    __shared__ __align__(16) bf16_t As[2][2][128 * 64];
    __shared__ __align__(16) bf16_t Bs[2][2][128 * 64];

    const int tid = threadIdx.x;
    const int l = tid & 63;
    const int w = tid >> 6;           // 0..7
    const int wm = w >> 2, wn = w & 3;
    const int lr = l & 15, lg = l >> 4;
    const int rb = (wn & 1) * 64 + lr;
    const int bh2 = wn >> 1;

    const int rowBase = blockIdx.x * 256;
    const int ct = blockIdx.y;

    const bf16_t* Ap = A + (size_t)rowBase * DIM;
    const bf16_t* Bp = B0 + (size_t)ct * 256 * DIM;

    f32x4 acc[8][4] = {};
    bf16x8 a0[4][2], a1[4][2];   // A half-operands [mi'][kk]
    bf16x8 bA[2][2], bB[2][2];   // B pairs: ni01 / ni23

    const int NT = DIM / 64;   // 64

    // ---- prologue: B(0), A(0), B(1); gate tile 0; pre-read a0,bA(0) ----
    stage_half(Bp, 0,  0, &Bs[0][0][0], tid, w);
    stage_half(Bp, 0,  1, &Bs[0][1][0], tid, w);
    stage_half(Ap, 0,  0, &As[0][0][0], tid, w);
    stage_half(Ap, 0,  1, &As[0][1][0], tid, w);
    stage_half(Bp, 64, 0, &Bs[1][0][0], tid, w);
    stage_half(Bp, 64, 1, &Bs[1][1][0], tid, w);
    asm volatile("s_waitcnt vmcnt(4)" ::: "memory");   // tile 0 landed
    fence_barrier();
    read_a4(a0, &As[0][wm][0], 0, lr, lg);
    read_b2(bA, &Bs[0][bh2][0], 0, rb, lg);

    for (int j = 0; j < NT; ++j) {
        const int s = j & 1;
        const bf16_t* Ah = &As[s][wm][0];
        const bf16_t* Bh = &Bs[s][bh2][0];
        const int ktA = ((j + 1 < NT) ? j + 1 : NT - 1) * 64;
        const int ktB = ((j + 2 < NT) ? j + 2 : NT - 1) * 64;

        // ---------- P1 ----------
        read_b2(bB, Bh, 1, rb, lg);
        stage_half(Ap, ktA, 0, &As[s ^ 1][0][0], tid, w);
        asm volatile("s_waitcnt lgkmcnt(4)" ::: "memory");   // a0,bA ready
        __builtin_amdgcn_s_setprio(1);
#pragma unroll
        for (int kk = 0; kk < 2; ++kk)
#pragma unroll
            for (int mi = 0; mi < 4; ++mi) {
                acc[mi][0] = __builtin_amdgcn_mfma_f32_16x16x32_bf16(a0[mi][kk], bA[0][kk], acc[mi][0], 0, 0, 0);
                acc[mi][1] = __builtin_amdgcn_mfma_f32_16x16x32_bf16(a0[mi][kk], bA[1][kk], acc[mi][1], 0, 0, 0);
            }
        __builtin_amdgcn_s_setprio(0);
        fence_barrier();

        // ---------- P2 ----------
        read_a4(a1, Ah, 1, lr, lg);
        stage_half(Ap, ktA, 1, &As[s ^ 1][1][0], tid, w);
        asm volatile("s_waitcnt lgkmcnt(8)" ::: "memory");   // bB ready
        __builtin_amdgcn_s_setprio(1);
#pragma unroll
        for (int kk = 0; kk < 2; ++kk)
#pragma unroll
            for (int mi = 0; mi < 4; ++mi) {
                acc[mi][2] = __builtin_amdgcn_mfma_f32_16x16x32_bf16(a0[mi][kk], bB[0][kk], acc[mi][2], 0, 0, 0);
                acc[mi][3] = __builtin_amdgcn_mfma_f32_16x16x32_bf16(a0[mi][kk], bB[1][kk], acc[mi][3], 0, 0, 0);
            }
        __builtin_amdgcn_s_setprio(0);
        fence_barrier();

        // ---------- P3 ----------
        stage_half(Bp, ktB, 0, &Bs[s][0][0], tid, w);
        asm volatile("s_waitcnt lgkmcnt(0)" ::: "memory");   // a1 ready
        __builtin_amdgcn_s_setprio(1);
#pragma unroll
        for (int kk = 0; kk < 2; ++kk)
#pragma unroll
            for (int mi = 0; mi < 4; ++mi) {
                acc[mi + 4][0] = __builtin_amdgcn_mfma_f32_16x16x32_bf16(a1[mi][kk], bA[0][kk], acc[mi + 4][0], 0, 0, 0);
                acc[mi + 4][1] = __builtin_amdgcn_mfma_f32_16x16x32_bf16(a1[mi][kk], bA[1][kk], acc[mi + 4][1], 0, 0, 0);
            }
        __builtin_amdgcn_s_setprio(0);
        fence_barrier();

        // ---------- P4 ----------
        stage_half(Bp, ktB, 1, &Bs[s][1][0], tid, w);
        __builtin_amdgcn_s_setprio(1);
#pragma unroll
        for (int kk = 0; kk < 2; ++kk)
#pragma unroll
            for (int mi = 0; mi < 4; ++mi) {
                acc[mi + 4][2] = __builtin_amdgcn_mfma_f32_16x16x32_bf16(a1[mi][kk], bB[0][kk], acc[mi + 4][2], 0, 0, 0);
                acc[mi + 4][3] = __builtin_amdgcn_mfma_f32_16x16x32_bf16(a1[mi][kk], bB[1][kk], acc[mi + 4][3], 0, 0, 0);
            }
        __builtin_amdgcn_s_setprio(0);
        asm volatile("s_waitcnt vmcnt(4)" ::: "memory");   // A(j+1) landed
        fence_barrier();
        if (j + 1 < NT) {
            read_a4(a0, &As[s ^ 1][wm][0], 0, lr, lg);
            read_b2(bA, &Bs[s ^ 1][bh2][0], 0, rb, lg);
        }
    }

    // ---- epilogue ----
#pragma unroll
    for (int mi = 0; mi < 8; ++mi) {
        int gmBase = rowBase + wm * 128 + mi * 16 + lg * 4;
#pragma unroll
        for (int ni = 0; ni < 4; ++ni) {
            f32x4 v4 = acc[mi][ni];
            int gn = ct * 256 + wn * 64 + ni * 16 + lr;
            if (MODE == 0) {
#pragma unroll
                for (int i = 0; i < 4; ++i)
                    outF[(size_t)(gmBase + i) * DIM + gn] = v4[i];
            } else { // MODE 3: fused QKV
                if (ct < 16) {          // Q rope -> Qr[b][h][s][d]
                    int h = gn >> 7, d = gn & 127, pi2 = d >> 1;
#pragma unroll
                    for (int i = 0; i < 4; ++i) {
                        float v = v4[i];
                        float pvv = __shfl_xor(v, 1);
                        int gm = gmBase + i;
                        int bb = gm >> 11, sidx = gm & (SEQ - 1);
                        float c = cosT[sidx * 64 + pi2], sn = sinT[sidx * 64 + pi2];
                        float o = (d & 1) ? (pvv * sn + v * c) : (v * c - pvv * sn);
                        outQ[((size_t)(bb * NH + h) * SEQ + sidx) * HD + d] = (bf16_t)o;
                    }
                } else if (ct < 20) {   // K rope -> Kr[b][kvh][s][d]
                    int kn = gn - 4096;
                    int h = kn >> 7, d = kn & 127, pi2 = d >> 1;
#pragma unroll
                    for (int i = 0; i < 4; ++i) {
                        float v = v4[i];
                        float pvv = __shfl_xor(v, 1);
                        int gm = gmBase + i;
                        int bb = gm >> 11, sidx = gm & (SEQ - 1);
                        float c = cosT[sidx * 64 + pi2], sn = sinT[sidx * 64 + pi2];
                        float o = (d & 1) ? (pvv * sn + v * c) : (v * c - pvv * sn);
                        outK[((size_t)(bb * NKVH + h) * SEQ + sidx) * HD + d] = (bf16_t)o;
                    }
                } else {                // V transpose -> Vt[b][kvh][d][s]
                    int vn = gn - 5120;
                    int kvh = vn >> 7, d = vn & 127;
#pragma unroll
                    for (int i = 0; i < 4; ++i) {
                        float dummy = __shfl_xor(v4[i], 1); (void)dummy;
                        int gm = gmBase + i;
                        int bb = gm >> 11, sidx = gm & (SEQ - 1);
                        outV[((size_t)(bb * NKVH + kvh) * HD + d) * SEQ + sidx] = (bf16_t)v4[i];
                    }
                }
            }
        }
    }
}

// ---------------- flash attention (causal, GQA) ---------------- (unchanged)
__global__ __launch_bounds__(256, 2)
void attn_fwd(const bf16_t* __restrict__ Qr,
              const bf16_t* __restrict__ Kr,
              const bf16_t* __restrict__ Vt,
              bf16_t* __restrict__ Ob) {
    __shared__ __align__(16) bf16_t Ks[2][64 * 128];   // [kv][d], swizzled
    __shared__ __align__(16) bf16_t Vs[2][128 * 64];   // [d][kv], swizzled
    __shared__ __align__(16) bf16_t Ps[4][32 * 64];    // per-wave P, swizzled

    const int tid = threadIdx.x;
    const int l  = tid & 63;
    const int w  = tid >> 6;
    const int lr = l & 15, lg = l >> 4;
    const int e  = lr & 7;

    const int qt  = 15 - (blockIdx.x >> 6);
    const int bh  = blockIdx.x & 63;
    const int b   = bh >> 5;
    const int h   = bh & 31;
    const int kvh = h >> 2;
    const int q0  = qt * 128;
    const int nt  = 2 * qt + 2;
    const int qmin = q0 + w * 32;

    const bf16_t* kbase = Kr + (size_t)(b * NKVH + kvh) * SEQ * HD;
    const bf16_t* vbase = Vt + (size_t)(b * NKVH + kvh) * HD * SEQ;

    bf16x8 qf[2][4];
    const bf16_t* qp = Qr + ((size_t)(b * NH + h) * SEQ + qmin + lr) * HD;
#pragma unroll
    for (int mi = 0; mi < 2; ++mi)
#pragma unroll
        for (int kk = 0; kk < 4; ++kk)
            qf[mi][kk] = *(const bf16x8*)(qp + (size_t)mi * 16 * HD + kk * 32 + lg * 8);

    f32x4 oacc[2][8] = {};
    float mrow[2] = {-1e30f, -1e30f};
    float lsum[2] = {0.f, 0.f};

#pragma unroll
    for (int t2 = 0; t2 < 4; ++t2) {
        int s = t2 * 256 + tid;
        { int r = s >> 4, g = (s & 15) ^ (r & 7);
          gload_lds16(kbase + (size_t)r * HD + g * 8,
                      &Ks[0][(size_t)(t2 * 256 + w * 64) * 8]); }
        { int r = s >> 3, g = (s & 7) ^ (r & 7);
          gload_lds16(vbase + (size_t)r * SEQ + g * 8,
                      &Vs[0][(size_t)(t2 * 256 + w * 64) * 8]); }
    }
    __syncthreads();

    int cur = 0;
    for (int t = 0; t < nt; ++t) {
        if (t + 1 < nt) {
            const int kv1 = (t + 1) * 64;
#pragma unroll
            for (int t2 = 0; t2 < 4; ++t2) {
                int s = t2 * 256 + tid;
                { int r = s >> 4, g = (s & 15) ^ (r & 7);
                  gload_lds16(kbase + (size_t)(kv1 + r) * HD + g * 8,
                              &Ks[cur ^ 1][(size_t)(t2 * 256 + w * 64) * 8]); }
                { int r = s >> 3, g = (s & 7) ^ (r & 7);
                  gload_lds16(vbase + (size_t)r * SEQ + kv1 + g * 8,
                              &Vs[cur ^ 1][(size_t)(t2 * 256 + w * 64) * 8]); }
            }
        }

        const bool active = (t * 64) <= (qmin + 31);
        if (active) {
            const bool needMask = (t * 64 + 63) > qmin;

            f32x4 sf[2][4] = {};
#pragma unroll
            for (int kk = 0; kk < 4; ++kk)
#pragma unroll
                for (int nf = 0; nf < 4; ++nf) {
                    bf16x8 kf = *(const bf16x8*)(
                        &Ks[cur][(nf * 16 + lr) * 128 + ((kk * 4 + lg) ^ e) * 8]);
#pragma unroll
                    for (int mi = 0; mi < 2; ++mi)
                        sf[mi][nf] = __builtin_amdgcn_mfma_f32_16x16x32_bf16(
                            kf, qf[mi][kk], sf[mi][nf], 0, 0, 0);
                }

            float aO[2][4];
#pragma unroll
            for (int mi = 0; mi < 2; ++mi) {
                const int qrow = qmin + mi * 16 + lr;
                float mt = -1e30f;
#pragma unroll
                for (int nf = 0; nf < 4; ++nf)
#pragma unroll
                    for (int i = 0; i < 4; ++i) {
                        float sc = sf[mi][nf][i] * SCALE;
                        if (needMask && (t * 64 + nf * 16 + lg * 4 + i) > qrow)
                            sc = -1e30f;
                        sf[mi][nf][i] = sc;
                        mt = fmaxf(mt, sc);
                    }
                mt = fmaxf(mt, __shfl_xor(mt, 16));
                mt = fmaxf(mt, __shfl_xor(mt, 32));
                float mnew = fmaxf(mrow[mi], mt);
                float alpha = __expf(mrow[mi] - mnew);
                mrow[mi] = mnew;
                float rs = 0.f;
#pragma unroll
                for (int nf = 0; nf < 4; ++nf)
#pragma unroll
                    for (int i = 0; i < 4; ++i) {
                        float p = __expf(sf[mi][nf][i] - mnew);
                        sf[mi][nf][i] = p;
                        rs += p;
                    }
                rs += __shfl_xor(rs, 16);
                rs += __shfl_xor(rs, 32);
                lsum[mi] = lsum[mi] * alpha + rs;
#pragma unroll
                for (int i = 0; i < 4; ++i)
                    aO[mi][i] = __shfl(alpha, lg * 4 + i);
            }

#pragma unroll
            for (int mi = 0; mi < 2; ++mi)
#pragma unroll
                for (int df = 0; df < 8; ++df)
#pragma unroll
                    for (int i = 0; i < 4; ++i)
                        oacc[mi][df][i] *= aO[mi][i];

#pragma unroll
            for (int mi = 0; mi < 2; ++mi)
#pragma unroll
                for (int nf = 0; nf < 4; ++nf) {
                    union { bf16_t bb[4]; uint2 u; } pk;
#pragma unroll
                    for (int i = 0; i < 4; ++i) pk.bb[i] = (bf16_t)sf[mi][nf][i];
                    int addr = (mi * 16 + lr) * 64 +
                               (((nf * 2 + (lg >> 1)) ^ e) << 3) + (lg & 1) * 4;
                    *(uint2*)(&Ps[w][addr]) = pk.u;
                }
            asm volatile("s_waitcnt lgkmcnt(0)" ::: "memory");
            __builtin_amdgcn_sched_barrier(0);

            bf16x8 pf[2][2];
#pragma unroll
            for (int mi = 0; mi < 2; ++mi)
#pragma unroll
                for (int k2 = 0; k2 < 2; ++k2)
                    pf[mi][k2] = *(const bf16x8*)(
                        &Ps[w][(mi * 16 + lr) * 64 + ((k2 * 4 + lg) ^ e) * 8]);
#pragma unroll
            for (int df = 0; df < 8; ++df)
#pragma unroll
                for (int k2 = 0; k2 < 2; ++k2) {
                    bf16x8 vf = *(const bf16x8*)(
                        &Vs[cur][(df * 16 + lr) * 64 + ((k2 * 4 + lg) ^ e) * 8]);
#pragma unroll
                    for (int mi = 0; mi < 2; ++mi)
                        oacc[mi][df] = __builtin_amdgcn_mfma_f32_16x16x32_bf16(
                            pf[mi][k2], vf, oacc[mi][df], 0, 0, 0);
                }
        }
        __syncthreads();
        cur ^= 1;
    }

#pragma unroll
    for (int mi = 0; mi < 2; ++mi) {
        float ls[4];
#pragma unroll
        for (int i = 0; i < 4; ++i)
            ls[i] = 1.f / __shfl(lsum[mi], lg * 4 + i);
#pragma unroll
        for (int df = 0; df < 8; ++df)
#pragma unroll
            for (int i = 0; i < 4; ++i) {
                float o = oacc[mi][df][i] * ls[i];
                int gm = b * SEQ + qmin + mi * 16 + lg * 4 + i;
                int gn = h * HD + df * 16 + lr;
                Ob[(size_t)gm * DIM + gn] = (bf16_t)o;
            }
    }
}

// ---------------- launcher ----------------
extern "C" void kernel_launch(void* const* d_in, const int* in_sizes, int n_in,
                              void* d_out, int out_size, void* d_ws, size_t ws_size,
                              hipStream_t stream) {
    const float* x    = (const float*)d_in[0];
    const float* cosT = (const float*)d_in[1];
    const float* sinT = (const float*)d_in[2];
    const float* wq   = (const float*)d_in[3];
    const float* wk   = (const float*)d_in[4];
    const float* wv   = (const float*)d_in[5];
    const float* wo   = (const float*)d_in[6];

    bf16_t* p = (bf16_t*)d_ws;
    bf16_t* xb  = p; p += (size_t)MTOT * DIM;
    bf16_t* wb  = p; p += (size_t)(DIM + 2 * NKVH * HD + DIM) * DIM;  // wq|wk|wv|wo
    bf16_t* Qr  = p; p += (size_t)MTOT * DIM;
    bf16_t* Kr  = p; p += (size_t)BATCH * NKVH * SEQ * HD;
    bf16_t* Vt  = p; p += (size_t)BATCH * NKVH * HD * SEQ;
    bf16_t* Ob  = p; p += (size_t)MTOT * DIM;

    bf16_t* wob = wb + (size_t)(DIM + 2 * NKVH * HD) * DIM;  // wo region

    cvt_f32_bf16<<<2048, 256, 0, stream>>>(x, xb, MTOT * DIM / 4);
    cvt_weights<<<2048, 256, 0, stream>>>(wq, wk, wv, wo, wb);

    // fused QKV: N = 4096 (Q) + 1024 (K) + 1024 (V) = 6144 -> 24 col tiles
    gemm8<3><<<dim3(16, 24), 512, 0, stream>>>(
        xb, wb, nullptr, Qr, Kr, Vt, cosT, sinT);

    attn_fwd<<<1024, 256, 0, stream>>>(Qr, Kr, Vt, Ob);

    gemm8<0><<<dim3(16, 16), 512, 0, stream>>>(
        Ob, wob, (float*)d_out, nullptr, nullptr, nullptr, nullptr, nullptr);
}